// Round 4
// baseline (959.379 us; speedup 1.0000x reference)
//
#include <hip/hip_runtime.h>

// ConvMGSA on MI355X. Inputs/outputs are FLOAT32 (per reference dtypes).
// Internal intermediates stored bf16 (2%-of-max threshold >> bf16 error).
// N=4 G=8 CIN=COUT=256 K=3 M=4 D=64 H=W=32 HW=1024.
//
// Buffers: ws[0:16MB]=K chain (k -> y2 -> f), ws[16:32MB]=V chain (v -> y3),
// d_out[0:16MB as bf16]=Q chain (q -> av -> ffn hidden; dead before the final
// LN2 f32 write, which reads only ws).
//
//  qkv:   per (n,g) GEMM 256x1024x256, writes PIXEL-major q/k/v [n][p][g*256+o]
//  attn:  per (n,p): scores[m,g,e,ij]=sum_d q*(k_ij+rel) (k=0 OOB, rel kept!),
//         softmax over 72, av[g,m,d]=sum attn*v (v=0 OOB). av aliases q buf.
//  wconv: C[p][o]=sum_i av[p][i]*w[o][i]+b -> channel-major y2
//  ln1:   LN_d( x + y2 ) over d=64 per (p,m,g); scramble == contiguous write
//  ffn:   two channel-major grouped GEMMs (relu between)
//  ln2:   LN_d( y3 + f ) -> d_out f32 (same scramble-contiguous write)

typedef unsigned short u16;
typedef unsigned int u32;

__device__ __forceinline__ float bf2f(u32 v) {
    u32 x = v << 16; float f; __builtin_memcpy(&f, &x, 4); return f;
}
__device__ __forceinline__ u16 f2bf(float f) {
    u32 x; __builtin_memcpy(&x, &f, 4);
    u32 r = x + 0x7fffu + ((x >> 16) & 1u);
    return (u16)(r >> 16);
}
__device__ __forceinline__ void ld8bf(const u16* p, float* o) {
    uint4 u = *(const uint4*)p;
    o[0] = bf2f(u.x & 0xffff); o[1] = bf2f(u.x >> 16);
    o[2] = bf2f(u.y & 0xffff); o[3] = bf2f(u.y >> 16);
    o[4] = bf2f(u.z & 0xffff); o[5] = bf2f(u.z >> 16);
    o[6] = bf2f(u.w & 0xffff); o[7] = bf2f(u.w >> 16);
}
__device__ __forceinline__ void ld8f(const float* p, float* o) {
    float4 a = *(const float4*)p, b = *(const float4*)(p + 4);
    o[0] = a.x; o[1] = a.y; o[2] = a.z; o[3] = a.w;
    o[4] = b.x; o[5] = b.y; o[6] = b.z; o[7] = b.w;
}
__device__ __forceinline__ void st4bf(u16* p, const float* v) {
    ushort4 s; s.x = f2bf(v[0]); s.y = f2bf(v[1]); s.z = f2bf(v[2]); s.w = f2bf(v[3]);
    *(ushort4*)p = s;
}

// ---------------- QKV: C[o][p] = sum_i W[g][o][i] * X[n][g][i][p]; store pixel-major ----
__global__ __launch_bounds__(256) void qkv_kernel(
    const float* __restrict__ x, const float* __restrict__ wq,
    const float* __restrict__ wk, const float* __restrict__ wv,
    u16* __restrict__ qt, u16* __restrict__ kt, u16* __restrict__ vt) {
    __shared__ float Xs[32][64];       // [i][p]
    __shared__ float Ws[3][32][69];    // [w][i][o], pad 69 -> conflict-free reads
    const int tid = threadIdx.x;
    const int pt = blockIdx.x, ot = blockIdx.y, ng = blockIdx.z;
    const int n = ng >> 3, g = ng & 7;
    const int p0 = pt << 6, o0 = ot << 6;
    const int tx = tid & 15, ty = tid >> 4;
    const float* xg = x + (size_t)ng * (256 * 1024);
    const float* wp[3] = { wq + (size_t)g * 65536, wk + (size_t)g * 65536, wv + (size_t)g * 65536 };
    float acc[3][4][4] = {};
    const int sx_i = tid >> 3, sx_p = (tid & 7) << 3;  // X stage: row i, 8 p's
    const int sw_o = tid >> 2, sw_i = (tid & 3) << 3;  // W stage: row o, 8 i's

    for (int i0 = 0; i0 < 256; i0 += 32) {
        float tmp[8];
        ld8f(xg + (size_t)(i0 + sx_i) * 1024 + p0 + sx_p, tmp);
        #pragma unroll
        for (int u = 0; u < 8; u++) Xs[sx_i][sx_p + u] = tmp[u];
        #pragma unroll
        for (int w = 0; w < 3; w++) {
            ld8f(wp[w] + (size_t)(o0 + sw_o) * 256 + i0 + sw_i, tmp);
            #pragma unroll
            for (int u = 0; u < 8; u++) Ws[w][sw_i + u][sw_o] = tmp[u];
        }
        __syncthreads();
        #pragma unroll
        for (int kk = 0; kk < 32; kk++) {
            float b[4];
            #pragma unroll
            for (int j = 0; j < 4; j++) b[j] = Xs[kk][tx * 4 + j];
            #pragma unroll
            for (int w = 0; w < 3; w++) {
                float a[4];
                #pragma unroll
                for (int i = 0; i < 4; i++) a[i] = Ws[w][kk][ty * 4 + i];
                #pragma unroll
                for (int i = 0; i < 4; i++)
                    #pragma unroll
                    for (int j = 0; j < 4; j++) acc[w][i][j] += a[i] * b[j];
            }
        }
        __syncthreads();
    }
    u16* outs[3] = { qt, kt, vt };
    #pragma unroll
    for (int w = 0; w < 3; w++)
        #pragma unroll
        for (int j = 0; j < 4; j++) {
            int p = p0 + tx * 4 + j;
            float v4[4] = { acc[w][0][j], acc[w][1][j], acc[w][2][j], acc[w][3][j] };
            st4bf(outs[w] + (size_t)(n * 1024 + p) * 2048 + g * 256 + o0 + ty * 4, v4);
        }
}

// ---------------- attention: one block per (n, pixel) ----------------
__global__ __launch_bounds__(256) void attn_kernel(
    const u16* __restrict__ qt, const u16* __restrict__ kt,
    const u16* __restrict__ vt, const float* __restrict__ hm,
    const float* __restrict__ wm, u16* __restrict__ av) {
    __shared__ float ks[8 * 260];        // per-e pad 260 -> distinct banks
    __shared__ float attn_s[32][73];     // [m*8+g][e*9+ij], pad 73
    const int tid = threadIdx.x;
    const int p = blockIdx.x, n = blockIdx.y;
    const int ph = p >> 5, pw = p & 31;
    const size_t pixbase = (size_t)(n * 1024 + p) * 2048;

    const int e_th = tid & 7;
    const int row = tid >> 3;              // m*8+g
    const int g_th = row & 7, m_th = row >> 3;

    float q[64];
    {
        const u16* qp = qt + pixbase + g_th * 256 + m_th * 64;
        #pragma unroll
        for (int c8 = 0; c8 < 8; c8++) ld8bf(qp + c8 * 8, q + c8 * 8);
    }
    const int c0 = tid << 3;               // staging / output channel base
    const int soff = (c0 >> 8) * 260 + (c0 & 255);
    // rel-pos source for this thread's 8 channels (c<1024 uniform per thread)
    const float* relsrc = (c0 < 1024) ? (hm + (size_t)c0 * 3) : (wm + (size_t)(c0 - 1024) * 3);
    const int rel_use_i = (c0 < 1024) ? 1 : 0;   // hm varies over i, wm over j

    float sc[9];
    #pragma unroll
    for (int ij = 0; ij < 9; ij++) {
        const int ii = ij / 3, jj = ij % 3;
        const int hs = ph + ii - 1, wsrc = pw + jj - 1;
        const bool inb = ((unsigned)hs < 32u) && ((unsigned)wsrc < 32u);
        const int ridx = rel_use_i ? ii : jj;
        float rv[8];
        #pragma unroll
        for (int u = 0; u < 8; u++) rv[u] = relsrc[u * 3 + ridx];
        if (inb) {
            float kv[8];
            ld8bf(kt + (size_t)(n * 1024 + hs * 32 + wsrc) * 2048 + c0, kv);
            #pragma unroll
            for (int u = 0; u < 8; u++) rv[u] += kv[u];
        }
        #pragma unroll
        for (int u = 0; u < 8; u++) ks[soff + u] = rv[u];
        __syncthreads();
        float s = 0.f;
        const float* kb = ks + e_th * 260 + m_th * 64;
        #pragma unroll
        for (int c = 0; c < 64; c++) s += q[c] * kb[c];
        sc[ij] = s;
        __syncthreads();
    }
    // softmax over (e, ij): 9 local + 8 lanes (e) per row
    float mx = sc[0];
    #pragma unroll
    for (int ij = 1; ij < 9; ij++) mx = fmaxf(mx, sc[ij]);
    mx = fmaxf(mx, __shfl_xor(mx, 1)); mx = fmaxf(mx, __shfl_xor(mx, 2)); mx = fmaxf(mx, __shfl_xor(mx, 4));
    float sum = 0.f;
    #pragma unroll
    for (int ij = 0; ij < 9; ij++) { sc[ij] = __expf(sc[ij] - mx); sum += sc[ij]; }
    sum += __shfl_xor(sum, 1); sum += __shfl_xor(sum, 2); sum += __shfl_xor(sum, 4);
    const float rinv = 1.f / sum;
    #pragma unroll
    for (int ij = 0; ij < 9; ij++) attn_s[row][e_th * 9 + ij] = sc[ij] * rinv;
    __syncthreads();

    // AV: thread owns 8 consecutive d of output channel c0..c0+7
    const int g_av = c0 >> 8, m_av = (c0 >> 6) & 3, d0 = c0 & 63;
    const int arow = m_av * 8 + g_av;
    float acc[8] = {};
    #pragma unroll
    for (int ij = 0; ij < 9; ij++) {
        const int hs = ph + ij / 3 - 1, wsrc = pw + ij % 3 - 1;
        const bool inb = ((unsigned)hs < 32u) && ((unsigned)wsrc < 32u);
        float vv[8];
        #pragma unroll
        for (int u = 0; u < 8; u++) vv[u] = 0.f;
        if (inb) ld8bf(vt + (size_t)(n * 1024 + hs * 32 + wsrc) * 2048 + c0, vv);
        #pragma unroll
        for (int u = 0; u < 8; u++) ks[soff + u] = vv[u];
        __syncthreads();
        #pragma unroll
        for (int e = 0; e < 8; e++) {
            const float a = attn_s[arow][e * 9 + ij];
            const float* vb = ks + e * 260 + m_av * 64 + d0;
            #pragma unroll
            for (int u = 0; u < 8; u++) acc[u] += a * vb[u];
        }
        __syncthreads();
    }
    st4bf(av + pixbase + c0, acc);
    st4bf(av + pixbase + c0 + 4, acc + 4);
}

// ---------------- w_conv: C[p][o] = sum_i A[p][i] * W[o][i] + b; store channel-major ----
__global__ __launch_bounds__(256) void wconv_kernel(
    const u16* __restrict__ av, const float* __restrict__ wc,
    const float* __restrict__ bc, u16* __restrict__ y2) {
    __shared__ float As[32][69];   // [i][p]
    __shared__ float Bs[32][69];   // [i][o]
    const int tid = threadIdx.x;
    const int pt = blockIdx.x, ot = blockIdx.y, ng = blockIdx.z;
    const int n = ng >> 3, g = ng & 7;
    const int p0 = pt << 6, o0 = ot << 6;
    const int tx = tid & 15, ty = tid >> 4;
    float acc[4][4] = {};
    const int sp = tid >> 2, si = (tid & 3) << 3;  // row (p or o), 8 i's

    for (int i0 = 0; i0 < 256; i0 += 32) {
        float tmp[8];
        ld8bf(av + (size_t)(n * 1024 + p0 + sp) * 2048 + g * 256 + i0 + si, tmp);
        #pragma unroll
        for (int u = 0; u < 8; u++) As[si + u][sp] = tmp[u];
        ld8f(wc + (size_t)(g * 256 + o0 + sp) * 256 + i0 + si, tmp);
        #pragma unroll
        for (int u = 0; u < 8; u++) Bs[si + u][sp] = tmp[u];
        __syncthreads();
        #pragma unroll
        for (int kk = 0; kk < 32; kk++) {
            float b[4], a[4];
            #pragma unroll
            for (int j = 0; j < 4; j++) b[j] = As[kk][tx * 4 + j];
            #pragma unroll
            for (int i = 0; i < 4; i++) a[i] = Bs[kk][ty * 4 + i];
            #pragma unroll
            for (int i = 0; i < 4; i++)
                #pragma unroll
                for (int j = 0; j < 4; j++) acc[i][j] += a[i] * b[j];
        }
        __syncthreads();
    }
    #pragma unroll
    for (int i = 0; i < 4; i++) {
        float bb = bc[g * 256 + o0 + ty * 4 + i];
        float v4[4] = { acc[i][0] + bb, acc[i][1] + bb, acc[i][2] + bb, acc[i][3] + bb };
        st4bf(y2 + (size_t)((n * 8 + g) * 256 + o0 + ty * 4 + i) * 1024 + p0 + tx * 4, v4);
    }
}

// ---------------- grouped 1x1 conv, bf16 in/out channel-major, f32 weights (FFN) ----------------
__global__ __launch_bounds__(256) void gconv_nn_kernel(
    const u16* __restrict__ inp, const float* __restrict__ wt,
    const float* __restrict__ bias, u16* __restrict__ out, int do_relu) {
    __shared__ float Bsh[32][64];  // [i][p]
    __shared__ float Wsh[32][69];  // [i][o]
    const int tid = threadIdx.x;
    const int pt = blockIdx.x, ot = blockIdx.y, ng = blockIdx.z;
    const int n = ng >> 3, g = ng & 7;
    const int p0 = pt << 6, o0 = ot << 6;
    const int tx = tid & 15, ty = tid >> 4;
    float acc[4][4] = {};
    const int sbi = tid >> 3, sbp = (tid & 7) << 3;
    const int swo = tid >> 2, swi = (tid & 3) << 3;

    for (int i0 = 0; i0 < 256; i0 += 32) {
        float tmp[8];
        ld8bf(inp + (size_t)((n * 8 + g) * 256 + i0 + sbi) * 1024 + p0 + sbp, tmp);
        #pragma unroll
        for (int u = 0; u < 8; u++) Bsh[sbi][sbp + u] = tmp[u];
        ld8f(wt + (size_t)(g * 256 + o0 + swo) * 256 + i0 + swi, tmp);
        #pragma unroll
        for (int u = 0; u < 8; u++) Wsh[swi + u][swo] = tmp[u];
        __syncthreads();
        #pragma unroll
        for (int kk = 0; kk < 32; kk++) {
            float b[4], a[4];
            #pragma unroll
            for (int j = 0; j < 4; j++) b[j] = Bsh[kk][tx * 4 + j];
            #pragma unroll
            for (int i = 0; i < 4; i++) a[i] = Wsh[kk][ty * 4 + i];
            #pragma unroll
            for (int i = 0; i < 4; i++)
                #pragma unroll
                for (int j = 0; j < 4; j++) acc[i][j] += a[i] * b[j];
        }
        __syncthreads();
    }
    #pragma unroll
    for (int i = 0; i < 4; i++) {
        float bb = bias[g * 256 + o0 + ty * 4 + i];
        float v4[4];
        #pragma unroll
        for (int j = 0; j < 4; j++) {
            float v = acc[i][j] + bb;
            v4[j] = do_relu ? fmaxf(v, 0.f) : v;
        }
        st4bf(out + (size_t)((n * 8 + g) * 256 + o0 + ty * 4 + i) * 1024 + p0 + tx * 4, v4);
    }
}

// ---------------- LN over d=64 of A+B; scramble-contiguous write ----------------
// A,B channel-major [n][g][m*64+d][p] (dtype per flag); out[n][p*2048+m*512+g*64+d]
__global__ __launch_bounds__(256) void ln_kernel(
    const void* __restrict__ A, int aF32, const void* __restrict__ B, int bF32,
    const float* __restrict__ gamma, const float* __restrict__ beta,
    void* __restrict__ out, int outF32) {
    __shared__ float s[64][68];    // [d][p], pad 68 (keeps 16B align)
    __shared__ float red[2][4][64];
    __shared__ float mu_s[64], rs_s[64], gam[64], bet[64];
    const int tid = threadIdx.x;
    const int pt = blockIdx.x, m = blockIdx.y, ng = blockIdx.z;
    const int n = ng >> 3, g = ng & 7;
    const int p0 = pt << 6;
    if (tid < 64) { gam[tid] = gamma[tid]; bet[tid] = beta[tid]; }

    const int sd = tid >> 2, sp = (tid & 3) << 4;
    {
        const size_t base = (size_t)((n * 8 + g) * 256 + m * 64 + sd) * 1024 + p0 + sp;
        #pragma unroll
        for (int half = 0; half < 2; half++) {
            float a8[8], b8[8];
            if (aF32) ld8f((const float*)A + base + half * 8, a8);
            else      ld8bf((const u16*)A + base + half * 8, a8);
            if (bF32) ld8f((const float*)B + base + half * 8, b8);
            else      ld8bf((const u16*)B + base + half * 8, b8);
            #pragma unroll
            for (int u = 0; u < 8; u++) s[sd][sp + half * 8 + u] = a8[u] + b8[u];
        }
    }
    __syncthreads();
    const int rp = tid & 63, rq = tid >> 6;
    float sm = 0.f, sq = 0.f;
    #pragma unroll
    for (int u = 0; u < 16; u++) { float v = s[rq * 16 + u][rp]; sm += v; sq += v * v; }
    red[0][rq][rp] = sm; red[1][rq][rp] = sq;
    __syncthreads();
    if (tid < 64) {
        float s2 = red[0][0][tid] + red[0][1][tid] + red[0][2][tid] + red[0][3][tid];
        float q2 = red[1][0][tid] + red[1][1][tid] + red[1][2][tid] + red[1][3][tid];
        float mu = s2 * (1.f / 64.f);
        float var = q2 * (1.f / 64.f) - mu * mu;
        mu_s[tid] = mu; rs_s[tid] = rsqrtf(var + 1e-5f);
    }
    __syncthreads();
    const int op = tid >> 2, od = (tid & 3) << 4;
    const float mu = mu_s[op], rs = rs_s[op];
    const size_t obase = (size_t)n * 2097152 + (size_t)(p0 + op) * 2048 + m * 512 + g * 64 + od;
    #pragma unroll
    for (int q4 = 0; q4 < 4; q4++) {
        float v4[4];
        #pragma unroll
        for (int u = 0; u < 4; u++) {
            int d = od + q4 * 4 + u;
            v4[u] = (s[d][op] - mu) * rs * gam[d] + bet[d];
        }
        if (outF32) {
            float4 f4; f4.x = v4[0]; f4.y = v4[1]; f4.z = v4[2]; f4.w = v4[3];
            *(float4*)((float*)out + obase + q4 * 4) = f4;
        } else {
            st4bf((u16*)out + obase + q4 * 4, v4);
        }
    }
}

extern "C" void kernel_launch(void* const* d_in, const int* in_sizes, int n_in,
                              void* d_out, int out_size, void* d_ws, size_t ws_size,
                              hipStream_t stream) {
    const float* x   = (const float*)d_in[0];
    const float* wq  = (const float*)d_in[1];
    const float* wk  = (const float*)d_in[2];
    const float* wv  = (const float*)d_in[3];
    const float* hm  = (const float*)d_in[4];
    const float* wm  = (const float*)d_in[5];
    const float* wc  = (const float*)d_in[6];
    const float* bc  = (const float*)d_in[7];
    const float* wf1 = (const float*)d_in[8];
    const float* bf1 = (const float*)d_in[9];
    const float* wf2 = (const float*)d_in[10];
    const float* bf2w = (const float*)d_in[11];
    const float* g1  = (const float*)d_in[12];
    const float* b1  = (const float*)d_in[13];
    const float* g2  = (const float*)d_in[14];
    const float* b2  = (const float*)d_in[15];
    char* ws = (char*)d_ws;
    u16* bufQ = (u16*)d_out;                     // bf16 scratch in d_out: q -> av -> ffn hidden
    u16* bufK = (u16*)(ws);                      // k -> y2 -> f
    u16* bufV = (u16*)(ws + 16777216);           // v -> y3

    qkv_kernel<<<dim3(16, 4, 32), dim3(256), 0, stream>>>(x, wq, wk, wv, bufQ, bufK, bufV);
    attn_kernel<<<dim3(1024, 4), dim3(256), 0, stream>>>(bufQ, bufK, bufV, hm, wm, bufQ);
    wconv_kernel<<<dim3(16, 4, 32), dim3(256), 0, stream>>>(bufQ, wc, bc, bufK);
    ln_kernel<<<dim3(16, 4, 32), dim3(256), 0, stream>>>(x, 1, bufK, 0, g1, b1, bufV, 0);
    gconv_nn_kernel<<<dim3(16, 4, 32), dim3(256), 0, stream>>>(bufV, wf1, bf1, bufQ, 1);
    gconv_nn_kernel<<<dim3(16, 4, 32), dim3(256), 0, stream>>>(bufQ, wf2, bf2w, bufK, 0);
    ln_kernel<<<dim3(16, 4, 32), dim3(256), 0, stream>>>(bufV, 0, bufK, 0, g2, b2, d_out, 1);
}

// Round 5
// 782.296 us; speedup vs baseline: 1.2264x; 1.2264x over previous
//
#include <hip/hip_runtime.h>

// ConvMGSA on MI355X. Inputs/outputs are FLOAT32 (per reference dtypes).
// Internal intermediates stored bf16 (2%-of-max threshold >> bf16 error).
// N=4 G=8 CIN=COUT=256 K=3 M=4 D=64 H=W=32 HW=1024.
//
// Buffers: ws[0:16MB]=K chain (k -> y2 -> f), ws[16:32MB]=V chain (v -> y3),
// d_out[0:16MB as bf16]=Q chain (q -> av -> ffn hidden; dead before the final
// LN2 f32 write, which reads only ws).
//
// R5: attn rewritten spill-free (R4: VGPR=256 + 560MB scratch writes = 465us).
//  - K/V read directly from global (L1-merged broadcasts), no K/V LDS staging
//  - c8-blocked QK dot (no q[64] live range), qrel[3] precompute for rel-pos
//  - block-uniform OOB mask branches; single __syncthreads (attn weights LDS)

typedef unsigned short u16;
typedef unsigned int u32;

__device__ __forceinline__ float bf2f(u32 v) {
    u32 x = v << 16; float f; __builtin_memcpy(&f, &x, 4); return f;
}
__device__ __forceinline__ u16 f2bf(float f) {
    u32 x; __builtin_memcpy(&x, &f, 4);
    u32 r = x + 0x7fffu + ((x >> 16) & 1u);
    return (u16)(r >> 16);
}
__device__ __forceinline__ void ld8bf(const u16* p, float* o) {
    uint4 u = *(const uint4*)p;
    o[0] = bf2f(u.x & 0xffff); o[1] = bf2f(u.x >> 16);
    o[2] = bf2f(u.y & 0xffff); o[3] = bf2f(u.y >> 16);
    o[4] = bf2f(u.z & 0xffff); o[5] = bf2f(u.z >> 16);
    o[6] = bf2f(u.w & 0xffff); o[7] = bf2f(u.w >> 16);
}
__device__ __forceinline__ void ld8f(const float* p, float* o) {
    float4 a = *(const float4*)p, b = *(const float4*)(p + 4);
    o[0] = a.x; o[1] = a.y; o[2] = a.z; o[3] = a.w;
    o[4] = b.x; o[5] = b.y; o[6] = b.z; o[7] = b.w;
}
__device__ __forceinline__ void st4bf(u16* p, const float* v) {
    ushort4 s; s.x = f2bf(v[0]); s.y = f2bf(v[1]); s.z = f2bf(v[2]); s.w = f2bf(v[3]);
    *(ushort4*)p = s;
}

// ---------------- QKV: C[o][p] = sum_i W[g][o][i] * X[n][g][i][p]; store pixel-major ----
__global__ __launch_bounds__(256) void qkv_kernel(
    const float* __restrict__ x, const float* __restrict__ wq,
    const float* __restrict__ wk, const float* __restrict__ wv,
    u16* __restrict__ qt, u16* __restrict__ kt, u16* __restrict__ vt) {
    __shared__ float Xs[32][64];       // [i][p]
    __shared__ float Ws[3][32][69];    // [w][i][o], pad 69 -> conflict-free reads
    const int tid = threadIdx.x;
    const int pt = blockIdx.x, ot = blockIdx.y, ng = blockIdx.z;
    const int n = ng >> 3, g = ng & 7;
    const int p0 = pt << 6, o0 = ot << 6;
    const int tx = tid & 15, ty = tid >> 4;
    const float* xg = x + (size_t)ng * (256 * 1024);
    const float* wp[3] = { wq + (size_t)g * 65536, wk + (size_t)g * 65536, wv + (size_t)g * 65536 };
    float acc[3][4][4] = {};
    const int sx_i = tid >> 3, sx_p = (tid & 7) << 3;  // X stage: row i, 8 p's
    const int sw_o = tid >> 2, sw_i = (tid & 3) << 3;  // W stage: row o, 8 i's

    for (int i0 = 0; i0 < 256; i0 += 32) {
        float tmp[8];
        ld8f(xg + (size_t)(i0 + sx_i) * 1024 + p0 + sx_p, tmp);
        #pragma unroll
        for (int u = 0; u < 8; u++) Xs[sx_i][sx_p + u] = tmp[u];
        #pragma unroll
        for (int w = 0; w < 3; w++) {
            ld8f(wp[w] + (size_t)(o0 + sw_o) * 256 + i0 + sw_i, tmp);
            #pragma unroll
            for (int u = 0; u < 8; u++) Ws[w][sw_i + u][sw_o] = tmp[u];
        }
        __syncthreads();
        #pragma unroll
        for (int kk = 0; kk < 32; kk++) {
            float b[4];
            #pragma unroll
            for (int j = 0; j < 4; j++) b[j] = Xs[kk][tx * 4 + j];
            #pragma unroll
            for (int w = 0; w < 3; w++) {
                float a[4];
                #pragma unroll
                for (int i = 0; i < 4; i++) a[i] = Ws[w][kk][ty * 4 + i];
                #pragma unroll
                for (int i = 0; i < 4; i++)
                    #pragma unroll
                    for (int j = 0; j < 4; j++) acc[w][i][j] += a[i] * b[j];
            }
        }
        __syncthreads();
    }
    u16* outs[3] = { qt, kt, vt };
    #pragma unroll
    for (int w = 0; w < 3; w++)
        #pragma unroll
        for (int j = 0; j < 4; j++) {
            int p = p0 + tx * 4 + j;
            float v4[4] = { acc[w][0][j], acc[w][1][j], acc[w][2][j], acc[w][3][j] };
            st4bf(outs[w] + (size_t)(n * 1024 + p) * 2048 + g * 256 + o0 + ty * 4, v4);
        }
}

// ---------------- attention: one block per (n, pixel), spill-free ----------------
__global__ __launch_bounds__(256) void attn_kernel(
    const u16* __restrict__ qt, const u16* __restrict__ kt,
    const u16* __restrict__ vt, const float* __restrict__ hm,
    const float* __restrict__ wm, u16* __restrict__ av) {
    __shared__ float attn_s[32][73];     // [m*8+g][e*9+ij]; 73 -> conflict-free AV reads
    const int tid = threadIdx.x;
    const int p = blockIdx.x, n = blockIdx.y;
    const int ph = p >> 5, pw = p & 31;
    const size_t nimg = (size_t)n * 1024;

    // block-uniform neighbor pixel ids + validity mask
    int npix[9]; unsigned inb = 0;
    #pragma unroll
    for (int ij = 0; ij < 9; ij++) {
        int hs = ph + ij / 3 - 1, ws = pw + ij % 3 - 1;
        npix[ij] = hs * 32 + ws;
        if (((unsigned)hs < 32u) && ((unsigned)ws < 32u)) inb |= (1u << ij);
    }

    // -------- QK phase: thread (row = m*8+g, e) --------
    const int e_th = tid & 7;
    const int row = tid >> 3, g_th = row & 7, m_th = row >> 3;
    const int cbase = e_th * 256 + m_th * 64;          // k channel base (e,m)
    const u16* qp = qt + (nimg + p) * 2048 + g_th * 256 + m_th * 64;
    const float* relbase = (e_th < 4) ? (hm + (size_t)cbase * 3)
                                      : (wm + (size_t)(cbase - 1024) * 3);

    float sc[9] = {};
    float qrel[3] = {};
    for (int c8 = 0; c8 < 8; c8++) {
        float q8[8];
        ld8bf(qp + c8 * 8, q8);
        // rel contribution: 24 contiguous floats = rel[(c8*8+u)*3 + idx]
        float r24[24];
        #pragma unroll
        for (int t = 0; t < 6; t++) {
            float4 f = *(const float4*)(relbase + c8 * 24 + t * 4);
            r24[t * 4] = f.x; r24[t * 4 + 1] = f.y; r24[t * 4 + 2] = f.z; r24[t * 4 + 3] = f.w;
        }
        #pragma unroll
        for (int u = 0; u < 8; u++) {
            qrel[0] += q8[u] * r24[u * 3];
            qrel[1] += q8[u] * r24[u * 3 + 1];
            qrel[2] += q8[u] * r24[u * 3 + 2];
        }
        for (int ij = 0; ij < 9; ij++) {
            if (inb & (1u << ij)) {
                float k8[8];
                ld8bf(kt + (nimg + npix[ij]) * 2048 + cbase + c8 * 8, k8);
                float s = sc[ij];
                #pragma unroll
                for (int u = 0; u < 8; u++) s += q8[u] * k8[u];
                sc[ij] = s;
            }
        }
    }
    // add rel term (OOB keeps rel-only score; idx = ii for e<4 else jj)
    #pragma unroll
    for (int ij = 0; ij < 9; ij++) {
        int idx = (e_th < 4) ? (ij / 3) : (ij % 3);
        sc[ij] += qrel[idx];
    }

    // softmax over (e, ij): 9 local + 8 lanes (e) per row
    float mx = sc[0];
    #pragma unroll
    for (int ij = 1; ij < 9; ij++) mx = fmaxf(mx, sc[ij]);
    mx = fmaxf(mx, __shfl_xor(mx, 1)); mx = fmaxf(mx, __shfl_xor(mx, 2)); mx = fmaxf(mx, __shfl_xor(mx, 4));
    float sum = 0.f;
    #pragma unroll
    for (int ij = 0; ij < 9; ij++) { sc[ij] = __expf(sc[ij] - mx); sum += sc[ij]; }
    sum += __shfl_xor(sum, 1); sum += __shfl_xor(sum, 2); sum += __shfl_xor(sum, 4);
    const float rinv = 1.f / sum;
    #pragma unroll
    for (int ij = 0; ij < 9; ij++) attn_s[row][e_th * 9 + ij] = sc[ij] * rinv;
    __syncthreads();

    // -------- AV phase: thread owns 8 d of output channel c0 = g*256+m*64+d0 --------
    const int c0 = tid << 3;
    const int g_av = c0 >> 8, m_av = (c0 >> 6) & 3, d0 = c0 & 63;
    const int arow = m_av * 8 + g_av;
    float acc[8] = {};
    for (int ij = 0; ij < 9; ij++) {
        if (!(inb & (1u << ij))) continue;           // v=0 outside
        const u16* vb = vt + (nimg + npix[ij]) * 2048 + m_av * 64 + d0;
        for (int e = 0; e < 8; e++) {
            const float a = attn_s[arow][e * 9 + ij];
            float v8[8];
            ld8bf(vb + e * 256, v8);
            #pragma unroll
            for (int u = 0; u < 8; u++) acc[u] += a * v8[u];
        }
    }
    st4bf(av + (nimg + p) * 2048 + c0, acc);
    st4bf(av + (nimg + p) * 2048 + c0 + 4, acc + 4);
}

// ---------------- w_conv: C[p][o] = sum_i A[p][i] * W[o][i] + b; store channel-major ----
__global__ __launch_bounds__(256) void wconv_kernel(
    const u16* __restrict__ av, const float* __restrict__ wc,
    const float* __restrict__ bc, u16* __restrict__ y2) {
    __shared__ float As[32][69];   // [i][p]
    __shared__ float Bs[32][69];   // [i][o]
    const int tid = threadIdx.x;
    const int pt = blockIdx.x, ot = blockIdx.y, ng = blockIdx.z;
    const int n = ng >> 3, g = ng & 7;
    const int p0 = pt << 6, o0 = ot << 6;
    const int tx = tid & 15, ty = tid >> 4;
    float acc[4][4] = {};
    const int sp = tid >> 2, si = (tid & 3) << 3;  // row (p or o), 8 i's

    for (int i0 = 0; i0 < 256; i0 += 32) {
        float tmp[8];
        ld8bf(av + (size_t)(n * 1024 + p0 + sp) * 2048 + g * 256 + i0 + si, tmp);
        #pragma unroll
        for (int u = 0; u < 8; u++) As[si + u][sp] = tmp[u];
        ld8f(wc + (size_t)(g * 256 + o0 + sp) * 256 + i0 + si, tmp);
        #pragma unroll
        for (int u = 0; u < 8; u++) Bs[si + u][sp] = tmp[u];
        __syncthreads();
        #pragma unroll
        for (int kk = 0; kk < 32; kk++) {
            float b[4], a[4];
            #pragma unroll
            for (int j = 0; j < 4; j++) b[j] = As[kk][tx * 4 + j];
            #pragma unroll
            for (int i = 0; i < 4; i++) a[i] = Bs[kk][ty * 4 + i];
            #pragma unroll
            for (int i = 0; i < 4; i++)
                #pragma unroll
                for (int j = 0; j < 4; j++) acc[i][j] += a[i] * b[j];
        }
        __syncthreads();
    }
    #pragma unroll
    for (int i = 0; i < 4; i++) {
        float bb = bc[g * 256 + o0 + ty * 4 + i];
        float v4[4] = { acc[i][0] + bb, acc[i][1] + bb, acc[i][2] + bb, acc[i][3] + bb };
        st4bf(y2 + (size_t)((n * 8 + g) * 256 + o0 + ty * 4 + i) * 1024 + p0 + tx * 4, v4);
    }
}

// ---------------- grouped 1x1 conv, bf16 in/out channel-major, f32 weights (FFN) ----------------
__global__ __launch_bounds__(256) void gconv_nn_kernel(
    const u16* __restrict__ inp, const float* __restrict__ wt,
    const float* __restrict__ bias, u16* __restrict__ out, int do_relu) {
    __shared__ float Bsh[32][64];  // [i][p]
    __shared__ float Wsh[32][69];  // [i][o]
    const int tid = threadIdx.x;
    const int pt = blockIdx.x, ot = blockIdx.y, ng = blockIdx.z;
    const int n = ng >> 3, g = ng & 7;
    const int p0 = pt << 6, o0 = ot << 6;
    const int tx = tid & 15, ty = tid >> 4;
    float acc[4][4] = {};
    const int sbi = tid >> 3, sbp = (tid & 7) << 3;
    const int swo = tid >> 2, swi = (tid & 3) << 3;

    for (int i0 = 0; i0 < 256; i0 += 32) {
        float tmp[8];
        ld8bf(inp + (size_t)((n * 8 + g) * 256 + i0 + sbi) * 1024 + p0 + sbp, tmp);
        #pragma unroll
        for (int u = 0; u < 8; u++) Bsh[sbi][sbp + u] = tmp[u];
        ld8f(wt + (size_t)(g * 256 + o0 + swo) * 256 + i0 + swi, tmp);
        #pragma unroll
        for (int u = 0; u < 8; u++) Wsh[swi + u][swo] = tmp[u];
        __syncthreads();
        #pragma unroll
        for (int kk = 0; kk < 32; kk++) {
            float b[4], a[4];
            #pragma unroll
            for (int j = 0; j < 4; j++) b[j] = Bsh[kk][tx * 4 + j];
            #pragma unroll
            for (int i = 0; i < 4; i++) a[i] = Wsh[kk][ty * 4 + i];
            #pragma unroll
            for (int i = 0; i < 4; i++)
                #pragma unroll
                for (int j = 0; j < 4; j++) acc[i][j] += a[i] * b[j];
        }
        __syncthreads();
    }
    #pragma unroll
    for (int i = 0; i < 4; i++) {
        float bb = bias[g * 256 + o0 + ty * 4 + i];
        float v4[4];
        #pragma unroll
        for (int j = 0; j < 4; j++) {
            float v = acc[i][j] + bb;
            v4[j] = do_relu ? fmaxf(v, 0.f) : v;
        }
        st4bf(out + (size_t)((n * 8 + g) * 256 + o0 + ty * 4 + i) * 1024 + p0 + tx * 4, v4);
    }
}

// ---------------- LN over d=64 of A+B; scramble-contiguous write ----------------
// A,B channel-major [n][g][m*64+d][p] (dtype per flag); out[n][p*2048+m*512+g*64+d]
__global__ __launch_bounds__(256) void ln_kernel(
    const void* __restrict__ A, int aF32, const void* __restrict__ B, int bF32,
    const float* __restrict__ gamma, const float* __restrict__ beta,
    void* __restrict__ out, int outF32) {
    __shared__ float s[64][68];    // [d][p], pad 68 (keeps 16B align)
    __shared__ float red[2][4][64];
    __shared__ float mu_s[64], rs_s[64], gam[64], bet[64];
    const int tid = threadIdx.x;
    const int pt = blockIdx.x, m = blockIdx.y, ng = blockIdx.z;
    const int n = ng >> 3, g = ng & 7;
    const int p0 = pt << 6;
    if (tid < 64) { gam[tid] = gamma[tid]; bet[tid] = beta[tid]; }

    const int sd = tid >> 2, sp = (tid & 3) << 4;
    {
        const size_t base = (size_t)((n * 8 + g) * 256 + m * 64 + sd) * 1024 + p0 + sp;
        #pragma unroll
        for (int half = 0; half < 2; half++) {
            float a8[8], b8[8];
            if (aF32) ld8f((const float*)A + base + half * 8, a8);
            else      ld8bf((const u16*)A + base + half * 8, a8);
            if (bF32) ld8f((const float*)B + base + half * 8, b8);
            else      ld8bf((const u16*)B + base + half * 8, b8);
            #pragma unroll
            for (int u = 0; u < 8; u++) s[sd][sp + half * 8 + u] = a8[u] + b8[u];
        }
    }
    __syncthreads();
    const int rp = tid & 63, rq = tid >> 6;
    float sm = 0.f, sq = 0.f;
    #pragma unroll
    for (int u = 0; u < 16; u++) { float v = s[rq * 16 + u][rp]; sm += v; sq += v * v; }
    red[0][rq][rp] = sm; red[1][rq][rp] = sq;
    __syncthreads();
    if (tid < 64) {
        float s2 = red[0][0][tid] + red[0][1][tid] + red[0][2][tid] + red[0][3][tid];
        float q2 = red[1][0][tid] + red[1][1][tid] + red[1][2][tid] + red[1][3][tid];
        float mu = s2 * (1.f / 64.f);
        float var = q2 * (1.f / 64.f) - mu * mu;
        mu_s[tid] = mu; rs_s[tid] = rsqrtf(var + 1e-5f);
    }
    __syncthreads();
    const int op = tid >> 2, od = (tid & 3) << 4;
    const float mu = mu_s[op], rs = rs_s[op];
    const size_t obase = (size_t)n * 2097152 + (size_t)(p0 + op) * 2048 + m * 512 + g * 64 + od;
    #pragma unroll
    for (int q4 = 0; q4 < 4; q4++) {
        float v4[4];
        #pragma unroll
        for (int u = 0; u < 4; u++) {
            int d = od + q4 * 4 + u;
            v4[u] = (s[d][op] - mu) * rs * gam[d] + bet[d];
        }
        if (outF32) {
            float4 f4; f4.x = v4[0]; f4.y = v4[1]; f4.z = v4[2]; f4.w = v4[3];
            *(float4*)((float*)out + obase + q4 * 4) = f4;
        } else {
            st4bf((u16*)out + obase + q4 * 4, v4);
        }
    }
}

extern "C" void kernel_launch(void* const* d_in, const int* in_sizes, int n_in,
                              void* d_out, int out_size, void* d_ws, size_t ws_size,
                              hipStream_t stream) {
    const float* x   = (const float*)d_in[0];
    const float* wq  = (const float*)d_in[1];
    const float* wk  = (const float*)d_in[2];
    const float* wv  = (const float*)d_in[3];
    const float* hm  = (const float*)d_in[4];
    const float* wm  = (const float*)d_in[5];
    const float* wc  = (const float*)d_in[6];
    const float* bc  = (const float*)d_in[7];
    const float* wf1 = (const float*)d_in[8];
    const float* bf1 = (const float*)d_in[9];
    const float* wf2 = (const float*)d_in[10];
    const float* bf2w = (const float*)d_in[11];
    const float* g1  = (const float*)d_in[12];
    const float* b1  = (const float*)d_in[13];
    const float* g2  = (const float*)d_in[14];
    const float* b2  = (const float*)d_in[15];
    char* ws = (char*)d_ws;
    u16* bufQ = (u16*)d_out;                     // bf16 scratch in d_out: q -> av -> ffn hidden
    u16* bufK = (u16*)(ws);                      // k -> y2 -> f
    u16* bufV = (u16*)(ws + 16777216);           // v -> y3

    qkv_kernel<<<dim3(16, 4, 32), dim3(256), 0, stream>>>(x, wq, wk, wv, bufQ, bufK, bufV);
    attn_kernel<<<dim3(1024, 4), dim3(256), 0, stream>>>(bufQ, bufK, bufV, hm, wm, bufQ);
    wconv_kernel<<<dim3(16, 4, 32), dim3(256), 0, stream>>>(bufQ, wc, bc, bufK);
    ln_kernel<<<dim3(16, 4, 32), dim3(256), 0, stream>>>(x, 1, bufK, 0, g1, b1, bufV, 0);
    gconv_nn_kernel<<<dim3(16, 4, 32), dim3(256), 0, stream>>>(bufV, wf1, bf1, bufQ, 1);
    gconv_nn_kernel<<<dim3(16, 4, 32), dim3(256), 0, stream>>>(bufQ, wf2, bf2w, bufK, 0);
    ln_kernel<<<dim3(16, 4, 32), dim3(256), 0, stream>>>(bufV, 0, bufK, 0, g2, b2, d_out, 1);
}

// Round 6
// 522.139 us; speedup vs baseline: 1.8374x; 1.4983x over previous
//
#include <hip/hip_runtime.h>

// ConvMGSA on MI355X. Inputs/outputs FLOAT32; intermediates bf16.
// N=4 G=8 CIN=COUT=256 K=3 M=4 D=64 H=W=32 HW=1024.
//
// R6: all four GEMM families -> bf16 MFMA (16x16x32), one templated kernel:
//   BMODE: 0=f32 i-major (x), 1=bf16 i-major (intermediates), 2=bf16 pixel-major (av)
//   OUTMODE: 0=bf16 pixel-major [p][g*256+o] (qkv), 1=bf16 channel-major +bias(+relu)
//   128x128 block tile, BK=32, f32->bf16 staging via v_perm pack; LDS-transpose
//   epilogue for channel-major stores.
// attn: interior-pixel fast path (branch-free, loads hoisted for MLP).

typedef unsigned short u16;
typedef unsigned int u32;
typedef __attribute__((ext_vector_type(8))) short bf16x8;
typedef __attribute__((ext_vector_type(4))) float f32x4;

__device__ __forceinline__ u32 fbits(float f) { u32 x; __builtin_memcpy(&x, &f, 4); return x; }
__device__ __forceinline__ float bf2f(u32 v) {
    u32 x = v << 16; float f; __builtin_memcpy(&f, &x, 4); return f;
}
__device__ __forceinline__ u16 f2bf(float f) {
    u32 x = fbits(f);
    u32 r = x + 0x7fffu + ((x >> 16) & 1u);
    return (u16)(r >> 16);
}
// fast round-to-bf16 (adds half-ulp then truncates); packs two into one u32
__device__ __forceinline__ u32 pack2bf(float a, float b) {
    return __builtin_amdgcn_perm(fbits(b) + 0x8000u, fbits(a) + 0x8000u, 0x07060302u);
}
__device__ __forceinline__ u16 bfr(float f) { return (u16)((fbits(f) + 0x8000u) >> 16); }

__device__ __forceinline__ void unpack8(uint4 u, float* o) {
    o[0] = bf2f(u.x & 0xffff); o[1] = bf2f(u.x >> 16);
    o[2] = bf2f(u.y & 0xffff); o[3] = bf2f(u.y >> 16);
    o[4] = bf2f(u.z & 0xffff); o[5] = bf2f(u.z >> 16);
    o[6] = bf2f(u.w & 0xffff); o[7] = bf2f(u.w >> 16);
}
__device__ __forceinline__ void ld8bf(const u16* p, float* o) { unpack8(*(const uint4*)p, o); }
__device__ __forceinline__ void ld8f(const float* p, float* o) {
    float4 a = *(const float4*)p, b = *(const float4*)(p + 4);
    o[0] = a.x; o[1] = a.y; o[2] = a.z; o[3] = a.w;
    o[4] = b.x; o[5] = b.y; o[6] = b.z; o[7] = b.w;
}
__device__ __forceinline__ void st4bf(u16* p, const float* v) {
    ushort4 s; s.x = f2bf(v[0]); s.y = f2bf(v[1]); s.z = f2bf(v[2]); s.w = f2bf(v[3]);
    *(ushort4*)p = s;
}

// ================= MFMA GEMM: C[o][p] = sum_i W[g][o][i] * B[i][p] =================
// A (weights): f32 [g][256][256] row-major (k-contiguous). M=256(o), N=1024(p), K=256.
// grid (pt=8, ot=2, ng=32), block 256 (4 waves, 64x64 wave tile, 4x4 16x16 frags).
template<int BMODE, int OUTMODE, int RELU>
__global__ __launch_bounds__(256) void gemm_kernel(
    const float* __restrict__ A, const void* __restrict__ B,
    const float* __restrict__ bias, u16* __restrict__ out) {
    __shared__ __align__(16) char smem[OUTMODE == 1 ? 64 * 132 * 4 : 20480];
    u16* Al = (u16*)smem;              // [128][40] bf16  (o, k)
    u16* Bl = (u16*)(smem + 10240);    // [128][40] bf16  (p, k)
    float* Cl = (float*)smem;          // [64][132] f32   (epilogue transpose)

    const int tid = threadIdx.x;
    const int pt = blockIdx.x, ot = blockIdx.y, ng = blockIdx.z;
    const int n = ng >> 3, g = ng & 7;
    const int p0 = pt << 7, o0 = ot << 7;
    const float* Ag = A + (size_t)g * 65536;

    const int l = tid & 63, w = tid >> 6;
    const int mq = w >> 1;                      // wave row (phase for epilogue)
    const int mw = mq << 6, nw = (w & 1) << 6;  // wave tile origin
    const int lrow = l & 15, lk = (l >> 4) << 3;

    f32x4 acc[4][4];
    #pragma unroll
    for (int i = 0; i < 4; i++)
        #pragma unroll
        for (int j = 0; j < 4; j++) acc[i][j] = (f32x4){0.f, 0.f, 0.f, 0.f};

    for (int k0 = 0; k0 < 256; k0 += 32) {
        // ---- stage A: 128 o-rows x 32 k (f32 -> bf16, rows k-contiguous) ----
        {
            const int r = tid >> 1, cb = (tid & 1) << 4;
            const float* src = Ag + (size_t)(o0 + r) * 256 + k0 + cb;
            u32* dst = (u32*)&Al[r * 40 + cb];
            #pragma unroll
            for (int q = 0; q < 4; q++) {
                float4 f = *(const float4*)(src + q * 4);
                dst[q * 2]     = pack2bf(f.x, f.y);
                dst[q * 2 + 1] = pack2bf(f.z, f.w);
            }
        }
        // ---- stage B into Bl[p][k] ----
        if (BMODE == 2) {        // av pixel-major bf16: rows already k-contiguous
            const int r = tid >> 1, cb = (tid & 1) << 4;
            const u16* src = (const u16*)B + (size_t)(n * 1024 + p0 + r) * 2048 + g * 256 + k0 + cb;
            *(uint4*)&Bl[r * 40 + cb]     = *(const uint4*)src;
            *(uint4*)&Bl[r * 40 + cb + 8] = *(const uint4*)(src + 8);
        } else {                 // i-major: transpose during staging
            const int kr = tid >> 3, pc = (tid & 7) << 4;
            if (BMODE == 0) {
                const float* src = (const float*)B + (size_t)(ng * 256 + k0 + kr) * 1024 + p0 + pc;
                #pragma unroll
                for (int q = 0; q < 4; q++) {
                    float4 f = *(const float4*)(src + q * 4);
                    Bl[(pc + q * 4 + 0) * 40 + kr] = bfr(f.x);
                    Bl[(pc + q * 4 + 1) * 40 + kr] = bfr(f.y);
                    Bl[(pc + q * 4 + 2) * 40 + kr] = bfr(f.z);
                    Bl[(pc + q * 4 + 3) * 40 + kr] = bfr(f.w);
                }
            } else {
                const u16* src = (const u16*)B + (size_t)(ng * 256 + k0 + kr) * 1024 + p0 + pc;
                uint4 v0 = *(const uint4*)src;
                uint4 v1 = *(const uint4*)(src + 8);
                u16 tmp[16];
                *(uint4*)&tmp[0] = v0; *(uint4*)&tmp[8] = v1;
                #pragma unroll
                for (int u = 0; u < 16; u++) Bl[(pc + u) * 40 + kr] = tmp[u];
            }
        }
        __syncthreads();
        bf16x8 af[4], bfg[4];
        #pragma unroll
        for (int i = 0; i < 4; i++) af[i]  = *(const bf16x8*)&Al[(mw + i * 16 + lrow) * 40 + lk];
        #pragma unroll
        for (int j = 0; j < 4; j++) bfg[j] = *(const bf16x8*)&Bl[(nw + j * 16 + lrow) * 40 + lk];
        #pragma unroll
        for (int i = 0; i < 4; i++)
            #pragma unroll
            for (int j = 0; j < 4; j++)
                acc[i][j] = __builtin_amdgcn_mfma_f32_16x16x32_bf16(af[i], bfg[j], acc[i][j], 0, 0, 0);
        __syncthreads();
    }

    if (OUTMODE == 0) {
        // pixel-major store: out[(n*1024+p)*2048 + g*256 + o], 4 consecutive o per lane
        #pragma unroll
        for (int i = 0; i < 4; i++) {
            const int orow = o0 + mw + i * 16 + ((l >> 4) << 2);
            #pragma unroll
            for (int j = 0; j < 4; j++) {
                const int p = p0 + nw + j * 16 + lrow;
                float v4[4] = { acc[i][j].x, acc[i][j].y, acc[i][j].z, acc[i][j].w };
                st4bf(out + (size_t)(n * 1024 + p) * 2048 + g * 256 + orow, v4);
            }
        }
    } else {
        // channel-major + bias(+relu) via LDS transpose, two 64-row phases
        for (int ph = 0; ph < 2; ph++) {
            __syncthreads();
            if (mq == ph) {
                #pragma unroll
                for (int i = 0; i < 4; i++) {
                    const int rl = i * 16 + ((l >> 4) << 2);
                    #pragma unroll
                    for (int j = 0; j < 4; j++) {
                        const int c = nw + j * 16 + lrow;
                        Cl[(rl    ) * 132 + c] = acc[i][j].x;
                        Cl[(rl + 1) * 132 + c] = acc[i][j].y;
                        Cl[(rl + 2) * 132 + c] = acc[i][j].z;
                        Cl[(rl + 3) * 132 + c] = acc[i][j].w;
                    }
                }
            }
            __syncthreads();
            {
                const int row = tid >> 2, pc = (tid & 3) << 5;
                const int og = o0 + ph * 64 + row;
                const float bb = bias ? bias[g * 256 + og] : 0.f;
                u32 pk[16];
                #pragma unroll
                for (int q = 0; q < 8; q++) {
                    float4 f = *(const float4*)&Cl[row * 132 + pc + q * 4];
                    float a0 = f.x + bb, a1 = f.y + bb, a2 = f.z + bb, a3 = f.w + bb;
                    if (RELU) {
                        a0 = fmaxf(a0, 0.f); a1 = fmaxf(a1, 0.f);
                        a2 = fmaxf(a2, 0.f); a3 = fmaxf(a3, 0.f);
                    }
                    pk[q * 2]     = pack2bf(a0, a1);
                    pk[q * 2 + 1] = pack2bf(a2, a3);
                }
                u16* dst = out + (size_t)(ng * 256 + og) * 1024 + p0 + pc;
                #pragma unroll
                for (int q = 0; q < 4; q++) *(uint4*)(dst + q * 8) = *(uint4*)&pk[q * 4];
            }
        }
    }
}

// ---------------- attention: one block per (n, pixel) ----------------
__global__ __launch_bounds__(256) void attn_kernel(
    const u16* __restrict__ qt, const u16* __restrict__ kt,
    const u16* __restrict__ vt, const float* __restrict__ hm,
    const float* __restrict__ wm, u16* __restrict__ av) {
    __shared__ float attn_s[32][73];
    const int tid = threadIdx.x;
    const int p = blockIdx.x, n = blockIdx.y;
    const int ph = p >> 5, pw = p & 31;
    const size_t nimg = (size_t)n * 1024;

    int npix[9]; unsigned inb = 0;
    #pragma unroll
    for (int ij = 0; ij < 9; ij++) {
        int hs = ph + ij / 3 - 1, ws = pw + ij % 3 - 1;
        npix[ij] = hs * 32 + ws;
        if (((unsigned)hs < 32u) && ((unsigned)ws < 32u)) inb |= (1u << ij);
    }

    const int e_th = tid & 7;
    const int row = tid >> 3, g_th = row & 7, m_th = row >> 3;
    const int cbase = e_th * 256 + m_th * 64;
    const u16* qp = qt + (nimg + p) * 2048 + g_th * 256 + m_th * 64;
    const float* relbase = (e_th < 4) ? (hm + (size_t)cbase * 3)
                                      : (wm + (size_t)(cbase - 1024) * 3);

    float sc[9] = {};
    float qrel[3] = {};
    if (inb == 0x1ffu) {
        // interior fast path: branch-free, loads hoisted
        for (int c8 = 0; c8 < 8; c8++) {
            float q8[8];
            ld8bf(qp + c8 * 8, q8);
            float r24[24];
            #pragma unroll
            for (int t = 0; t < 6; t++) {
                float4 f = *(const float4*)(relbase + c8 * 24 + t * 4);
                r24[t * 4] = f.x; r24[t * 4 + 1] = f.y; r24[t * 4 + 2] = f.z; r24[t * 4 + 3] = f.w;
            }
            uint4 kr[9];
            #pragma unroll
            for (int ij = 0; ij < 9; ij++)
                kr[ij] = *(const uint4*)(kt + (nimg + npix[ij]) * 2048 + cbase + c8 * 8);
            #pragma unroll
            for (int u = 0; u < 8; u++) {
                qrel[0] += q8[u] * r24[u * 3];
                qrel[1] += q8[u] * r24[u * 3 + 1];
                qrel[2] += q8[u] * r24[u * 3 + 2];
            }
            #pragma unroll
            for (int ij = 0; ij < 9; ij++) {
                float k8[8];
                unpack8(kr[ij], k8);
                float s = sc[ij];
                #pragma unroll
                for (int u = 0; u < 8; u++) s += q8[u] * k8[u];
                sc[ij] = s;
            }
        }
    } else {
        for (int c8 = 0; c8 < 8; c8++) {
            float q8[8];
            ld8bf(qp + c8 * 8, q8);
            float r24[24];
            #pragma unroll
            for (int t = 0; t < 6; t++) {
                float4 f = *(const float4*)(relbase + c8 * 24 + t * 4);
                r24[t * 4] = f.x; r24[t * 4 + 1] = f.y; r24[t * 4 + 2] = f.z; r24[t * 4 + 3] = f.w;
            }
            #pragma unroll
            for (int u = 0; u < 8; u++) {
                qrel[0] += q8[u] * r24[u * 3];
                qrel[1] += q8[u] * r24[u * 3 + 1];
                qrel[2] += q8[u] * r24[u * 3 + 2];
            }
            for (int ij = 0; ij < 9; ij++) {
                if (inb & (1u << ij)) {
                    float k8[8];
                    ld8bf(kt + (nimg + npix[ij]) * 2048 + cbase + c8 * 8, k8);
                    float s = sc[ij];
                    #pragma unroll
                    for (int u = 0; u < 8; u++) s += q8[u] * k8[u];
                    sc[ij] = s;
                }
            }
        }
    }
    #pragma unroll
    for (int ij = 0; ij < 9; ij++) {
        int idx = (e_th < 4) ? (ij / 3) : (ij % 3);
        sc[ij] += qrel[idx];
    }

    float mx = sc[0];
    #pragma unroll
    for (int ij = 1; ij < 9; ij++) mx = fmaxf(mx, sc[ij]);
    mx = fmaxf(mx, __shfl_xor(mx, 1)); mx = fmaxf(mx, __shfl_xor(mx, 2)); mx = fmaxf(mx, __shfl_xor(mx, 4));
    float sum = 0.f;
    #pragma unroll
    for (int ij = 0; ij < 9; ij++) { sc[ij] = __expf(sc[ij] - mx); sum += sc[ij]; }
    sum += __shfl_xor(sum, 1); sum += __shfl_xor(sum, 2); sum += __shfl_xor(sum, 4);
    const float rinv = 1.f / sum;
    #pragma unroll
    for (int ij = 0; ij < 9; ij++) attn_s[row][e_th * 9 + ij] = sc[ij] * rinv;
    __syncthreads();

    const int c0 = tid << 3;
    const int m_av = (c0 >> 6) & 3, d0 = c0 & 63;
    const int arow = m_av * 8 + (c0 >> 8);
    float acc[8] = {};
    if (inb == 0x1ffu) {
        for (int ij = 0; ij < 9; ij++) {
            const u16* vb = vt + (nimg + npix[ij]) * 2048 + m_av * 64 + d0;
            uint4 vr[8];
            #pragma unroll
            for (int e = 0; e < 8; e++) vr[e] = *(const uint4*)(vb + e * 256);
            #pragma unroll
            for (int e = 0; e < 8; e++) {
                const float a = attn_s[arow][e * 9 + ij];
                float v8[8];
                unpack8(vr[e], v8);
                #pragma unroll
                for (int u = 0; u < 8; u++) acc[u] += a * v8[u];
            }
        }
    } else {
        for (int ij = 0; ij < 9; ij++) {
            if (!(inb & (1u << ij))) continue;
            const u16* vb = vt + (nimg + npix[ij]) * 2048 + m_av * 64 + d0;
            for (int e = 0; e < 8; e++) {
                const float a = attn_s[arow][e * 9 + ij];
                float v8[8];
                ld8bf(vb + e * 256, v8);
                #pragma unroll
                for (int u = 0; u < 8; u++) acc[u] += a * v8[u];
            }
        }
    }
    st4bf(av + (nimg + p) * 2048 + c0, acc);
    st4bf(av + (nimg + p) * 2048 + c0 + 4, acc + 4);
}

// ---------------- LN over d=64 of A+B; scramble-contiguous write ----------------
__global__ __launch_bounds__(256) void ln_kernel(
    const void* __restrict__ A, int aF32, const void* __restrict__ B, int bF32,
    const float* __restrict__ gamma, const float* __restrict__ beta,
    void* __restrict__ out, int outF32) {
    __shared__ float s[64][68];
    __shared__ float red[2][4][64];
    __shared__ float mu_s[64], rs_s[64], gam[64], bet[64];
    const int tid = threadIdx.x;
    const int pt = blockIdx.x, m = blockIdx.y, ng = blockIdx.z;
    const int n = ng >> 3, g = ng & 7;
    const int p0 = pt << 6;
    if (tid < 64) { gam[tid] = gamma[tid]; bet[tid] = beta[tid]; }

    const int sd = tid >> 2, sp = (tid & 3) << 4;
    {
        const size_t base = (size_t)((n * 8 + g) * 256 + m * 64 + sd) * 1024 + p0 + sp;
        #pragma unroll
        for (int half = 0; half < 2; half++) {
            float a8[8], b8[8];
            if (aF32) ld8f((const float*)A + base + half * 8, a8);
            else      ld8bf((const u16*)A + base + half * 8, a8);
            if (bF32) ld8f((const float*)B + base + half * 8, b8);
            else      ld8bf((const u16*)B + base + half * 8, b8);
            #pragma unroll
            for (int u = 0; u < 8; u++) s[sd][sp + half * 8 + u] = a8[u] + b8[u];
        }
    }
    __syncthreads();
    const int rp = tid & 63, rq = tid >> 6;
    float sm = 0.f, sq = 0.f;
    #pragma unroll
    for (int u = 0; u < 16; u++) { float v = s[rq * 16 + u][rp]; sm += v; sq += v * v; }
    red[0][rq][rp] = sm; red[1][rq][rp] = sq;
    __syncthreads();
    if (tid < 64) {
        float s2 = red[0][0][tid] + red[0][1][tid] + red[0][2][tid] + red[0][3][tid];
        float q2 = red[1][0][tid] + red[1][1][tid] + red[1][2][tid] + red[1][3][tid];
        float mu = s2 * (1.f / 64.f);
        float var = q2 * (1.f / 64.f) - mu * mu;
        mu_s[tid] = mu; rs_s[tid] = rsqrtf(var + 1e-5f);
    }
    __syncthreads();
    const int op = tid >> 2, od = (tid & 3) << 4;
    const float mu = mu_s[op], rs = rs_s[op];
    const size_t obase = (size_t)n * 2097152 + (size_t)(p0 + op) * 2048 + m * 512 + g * 64 + od;
    #pragma unroll
    for (int q4 = 0; q4 < 4; q4++) {
        float v4[4];
        #pragma unroll
        for (int u = 0; u < 4; u++) {
            int d = od + q4 * 4 + u;
            v4[u] = (s[d][op] - mu) * rs * gam[d] + bet[d];
        }
        if (outF32) {
            float4 f4; f4.x = v4[0]; f4.y = v4[1]; f4.z = v4[2]; f4.w = v4[3];
            *(float4*)((float*)out + obase + q4 * 4) = f4;
        } else {
            st4bf((u16*)out + obase + q4 * 4, v4);
        }
    }
}

extern "C" void kernel_launch(void* const* d_in, const int* in_sizes, int n_in,
                              void* d_out, int out_size, void* d_ws, size_t ws_size,
                              hipStream_t stream) {
    const float* x   = (const float*)d_in[0];
    const float* wq  = (const float*)d_in[1];
    const float* wk  = (const float*)d_in[2];
    const float* wv  = (const float*)d_in[3];
    const float* hm  = (const float*)d_in[4];
    const float* wm  = (const float*)d_in[5];
    const float* wc  = (const float*)d_in[6];
    const float* bc  = (const float*)d_in[7];
    const float* wf1 = (const float*)d_in[8];
    const float* bf1 = (const float*)d_in[9];
    const float* wf2 = (const float*)d_in[10];
    const float* bf2w = (const float*)d_in[11];
    const float* g1  = (const float*)d_in[12];
    const float* b1  = (const float*)d_in[13];
    const float* g2  = (const float*)d_in[14];
    const float* b2  = (const float*)d_in[15];
    char* ws = (char*)d_ws;
    u16* bufQ = (u16*)d_out;                     // bf16 scratch in d_out: q -> av -> ffn hidden
    u16* bufK = (u16*)(ws);                      // k -> y2 -> f
    u16* bufV = (u16*)(ws + 16777216);           // v -> y3

    const dim3 gg(8, 2, 32), gb(256);
    gemm_kernel<0, 0, 0><<<gg, gb, 0, stream>>>(wq, x, nullptr, bufQ);
    gemm_kernel<0, 0, 0><<<gg, gb, 0, stream>>>(wk, x, nullptr, bufK);
    gemm_kernel<0, 0, 0><<<gg, gb, 0, stream>>>(wv, x, nullptr, bufV);
    attn_kernel<<<dim3(1024, 4), gb, 0, stream>>>(bufQ, bufK, bufV, hm, wm, bufQ);
    gemm_kernel<2, 1, 0><<<gg, gb, 0, stream>>>(wc, bufQ, bc, bufK);
    ln_kernel<<<dim3(16, 4, 32), gb, 0, stream>>>(x, 1, bufK, 0, g1, b1, bufV, 0);
    gemm_kernel<1, 1, 1><<<gg, gb, 0, stream>>>(wf1, bufV, bf1, bufQ);
    gemm_kernel<1, 1, 0><<<gg, gb, 0, stream>>>(wf2, bufQ, bf2w, bufK);
    ln_kernel<<<dim3(16, 4, 32), gb, 0, stream>>>(bufV, 0, bufK, 0, g2, b2, d_out, 1);
}